// Round 6
// baseline (87.794 us; speedup 1.0000x reference)
//
#include <hip/hip_runtime.h>
#include <hip/hip_bf16.h>

// Chamfer loss: B=32, N=M=2048, D=3.
// loss[b] = 0.5 * ( sum_n ma[n]*min_m d2(a_n,b_m) + sum_m mb[m]*min_n d2(b_m,a_n) )
// masked pairs -> BIG^2 = 1e16 (exact in fp32: a2 < ulp(1e16)).
//
// R6: main was invariant ~35us across R3-R5 regardless of VALU packing ->
// stream-bandwidth-bound theory: every wave reads the whole 32KB slice, so
// halve total LDS traffic by doubling rows/wave to 16 (GX 32->16, 1024 blocks
// = exactly one 4-blocks/CU occupancy round, no tail). Rows in SGPRs, point-
// pair SoA LDS for v_pk_fma_f32, 1-deep prefetch, no atomics, no min-waves cap.
#define B_    32
#define N_    2048
#define M_    2048
#define RW_   16       // rows per wave
#define GX_   16       // n-chunks per (b,dir): 2048 / (8 waves * 16 rows)
#define BIG2  1.0e16f

typedef float v2f __attribute__((ext_vector_type(2)));

__device__ __forceinline__ v2f v2_fma(v2f a, v2f b, v2f c) {
#if __has_builtin(__builtin_elementwise_fma)
    return __builtin_elementwise_fma(a, b, c);
#else
    v2f r; r.x = fmaf(a.x, b.x, c.x); r.y = fmaf(a.y, b.y, c.y); return r;
#endif
}
__device__ __forceinline__ v2f v2_min(v2f a, v2f b) {
#if __has_builtin(__builtin_elementwise_min)
    return __builtin_elementwise_min(a, b);
#else
    v2f r; r.x = fminf(a.x, b.x); r.y = fminf(a.y, b.y); return r;
#endif
}
__device__ __forceinline__ v2f v2_splat(float s) { return (v2f){ s, s }; }

union F4V2 { float4 f4; struct { v2f lo, hi; } v; };

// Main: grid (GX_, B_, 2), 512 threads (8 waves). Wave wv owns rows
// [bx*128 + wv*16, +16) in SGPRs. Inner side staged in LDS as point-PAIR SoA:
//   sqA[p] = {-2x_{2p}, -2x_{2p+1}, -2y_{2p}, -2y_{2p+1}}
//   sqB[p] = {-2z_{2p}, -2z_{2p+1},  w_{2p},   w_{2p+1}}   (w = mask?|p|^2:1e16)
// Tile = 64 lanes x 2 points = 128 points; per tile: 2 ds_read_b128 +
// (3 pk_fma + 1 pk_min) x 16 rows.
__global__ __launch_bounds__(512) void chamfer_main(
    const int* __restrict__ o_w, const float* __restrict__ o_pts,
    const int* __restrict__ t_w, const float* __restrict__ t_pts,
    float* __restrict__ partials)
{
    const int dir  = blockIdx.z;
    const int b    = blockIdx.y;
    const int tid  = threadIdx.x;
    const int lane = tid & 63;
    const int wv   = tid >> 6;
    const int row0 = blockIdx.x * (8 * RW_) + wv * RW_;

    const int*   wa; const float* pa;   // outer (row) side
    const int*   wb; const float* pb;   // inner (streamed) side
    if (dir == 0) { wa = o_w; pa = o_pts; wb = t_w; pb = t_pts; }
    else          { wa = t_w; pa = t_pts; wb = o_w; pb = o_pts; }

    __shared__ float4 sqA[M_ / 2];      // 16 KB
    __shared__ float4 sqB[M_ / 2];      // 16 KB
    __shared__ float  wsum[8];

    // ---- Stage inner slice: 512 threads x 2 pair-slots, coalesced float2.
    {
        const float2* src2 = (const float2*)(pb + (size_t)b * M_ * 3);
        const int2*   wb2  = (const int2*)(wb + (size_t)b * M_);
        #pragma unroll
        for (int k = 0; k < 2; ++k) {
            int p = tid + k * 512;                     // pair index 0..1023
            float2 u0 = src2[p * 3 + 0];
            float2 u1 = src2[p * 3 + 1];
            float2 u2 = src2[p * 3 + 2];
            int2   mm = wb2[p];
            float x0 = u0.x, y0 = u0.y, z0 = u1.x;
            float x1 = u1.y, y1 = u2.x, z1 = u2.y;
            float n20 = fmaf(x0, x0, fmaf(y0, y0, z0 * z0));
            float n21 = fmaf(x1, x1, fmaf(y1, y1, z1 * z1));
            sqA[p] = make_float4(-2.f * x0, -2.f * x1, -2.f * y0, -2.f * y1);
            sqB[p] = make_float4(-2.f * z0, -2.f * z1,
                                 mm.x ? n20 : BIG2, mm.y ? n21 : BIG2);
        }
    }

    // ---- Row constants into SGPRs (wave-uniform base -> s_loads).
    int base = __builtin_amdgcn_readfirstlane((b * N_ + row0) * 3);
    const float* rp = pa + base;
    float rx[RW_], ry[RW_], rz[RW_];
    #pragma unroll
    for (int r = 0; r < RW_; ++r) {
        rx[r] = rp[3 * r + 0];
        ry[r] = rp[3 * r + 1];
        rz[r] = rp[3 * r + 2];
    }
    __syncthreads();

    v2f acc[RW_];
    #pragma unroll
    for (int r = 0; r < RW_; ++r) acc[r] = v2_splat(3.4e38f);

    // ---- Inner loop: 16 tiles of 128 points, 1-deep LDS prefetch.
    F4V2 qa, qb, na, nb;
    qa.f4 = sqA[lane];
    qb.f4 = sqB[lane];
    #pragma unroll 2
    for (int t = 0; t < M_ / 128; ++t) {
        if (t + 1 < M_ / 128) {
            na.f4 = sqA[(t + 1) * 64 + lane];
            nb.f4 = sqB[(t + 1) * 64 + lane];
        }
        v2f xs = qa.v.lo, ys = qa.v.hi, zs = qb.v.lo, ws = qb.v.hi;
        #pragma unroll
        for (int r = 0; r < RW_; ++r) {
            v2f d = v2_fma(v2_splat(rx[r]), xs,
                    v2_fma(v2_splat(ry[r]), ys,
                    v2_fma(v2_splat(rz[r]), zs, ws)));
            acc[r] = v2_min(acc[r], d);
        }
        qa = na; qb = nb;
    }

    // ---- Cross-lane min per row, epilogue, block reduce, one store.
    int mbase = __builtin_amdgcn_readfirstlane(b * N_ + row0);
    const int* wp = wa + mbase;
    float sum = 0.0f;
    #pragma unroll
    for (int r = 0; r < RW_; ++r) {
        float m = fminf(acc[r].x, acc[r].y);
        #pragma unroll
        for (int off = 32; off; off >>= 1)
            m = fminf(m, __shfl_xor(m, off, 64));
        float a2 = fmaf(rx[r], rx[r], fmaf(ry[r], ry[r], rz[r] * rz[r]));
        float d2 = fmaxf(a2 + m, 0.0f);
        sum += (wp[r] != 0) ? d2 : 0.0f;
    }
    if (lane == 0) wsum[wv] = sum;
    __syncthreads();
    if (tid == 0) {
        float s = 0.f;
        #pragma unroll
        for (int i = 0; i < 8; ++i) s += wsum[i];
        partials[((size_t)b * 2 + dir) * GX_ + blockIdx.x] = s;
    }
}

// Finish: one block, 256 threads. Thread t: b = t>>3, k = t&7. The 32
// partials of batch b are read as 8 float4; 3-step shfl reduce in the
// 8-lane group.
__global__ __launch_bounds__(256) void chamfer_finish(
    const float* __restrict__ partials, float* __restrict__ loss)
{
    int t = threadIdx.x;
    int b = t >> 3, k = t & 7;
    const float4* p4 = (const float4*)(partials + b * (2 * GX_));
    float4 u = p4[k];
    float s = (u.x + u.y) + (u.z + u.w);
    #pragma unroll
    for (int off = 4; off; off >>= 1) s += __shfl_xor(s, off, 64);
    if (k == 0) loss[b] = 0.5f * s;
}

// ---------- Fallback (ws too small): prep-on-the-fly + atomics ----------
__global__ void chamfer_zero(float* __restrict__ loss)
{
    if (threadIdx.x < B_) loss[threadIdx.x] = 0.0f;
}

__global__ __launch_bounds__(256) void chamfer_nolds(
    const int* __restrict__ o_w, const float* __restrict__ o_pts,
    const int* __restrict__ t_w, const float* __restrict__ t_pts,
    float* __restrict__ loss)
{
    const int dir  = blockIdx.z;
    const int b    = blockIdx.y;
    const int lane = threadIdx.x & 63;
    const int wv   = threadIdx.x >> 6;
    const int row0 = (blockIdx.x * 4 + wv) * 16;

    const int*   __restrict__ wa = (dir == 0) ? o_w   : t_w;
    const float* __restrict__ pa = (dir == 0) ? o_pts : t_pts;
    const int*   __restrict__ wb = (dir == 0) ? t_w   : o_w;
    const float* __restrict__ pb = (dir == 0) ? t_pts : o_pts;

    int base = __builtin_amdgcn_readfirstlane((b * N_ + row0) * 3);
    const float* rp = pa + base;
    float rx[16], ry[16], rz[16];
    #pragma unroll
    for (int r = 0; r < 16; ++r) {
        rx[r] = rp[3 * r + 0];
        ry[r] = rp[3 * r + 1];
        rz[r] = rp[3 * r + 2];
    }
    float acc[16];
    #pragma unroll
    for (int r = 0; r < 16; ++r) acc[r] = 3.4e38f;

    #pragma unroll 2
    for (int t = 0; t < M_ / 64; ++t) {
        int ib = b * M_ + t * 64 + lane;
        float bx = pb[ib * 3 + 0], by = pb[ib * 3 + 1], bz = pb[ib * 3 + 2];
        float n2 = fmaf(bx, bx, fmaf(by, by, bz * bz));
        float qw = (wb[ib] != 0) ? n2 : BIG2;
        float qx = -2.0f * bx, qy = -2.0f * by, qz = -2.0f * bz;
        #pragma unroll
        for (int r = 0; r < 16; ++r) {
            float d = fmaf(rx[r], qx, fmaf(ry[r], qy, fmaf(rz[r], qz, qw)));
            acc[r] = fminf(acc[r], d);
        }
    }
    #pragma unroll
    for (int r = 0; r < 16; ++r) {
        float v = acc[r];
        #pragma unroll
        for (int off = 32; off; off >>= 1) v = fminf(v, __shfl_xor(v, off, 64));
        acc[r] = v;
    }
    int mbase = __builtin_amdgcn_readfirstlane(b * N_ + row0);
    const int* wp = wa + mbase;
    float sum = 0.0f;
    #pragma unroll
    for (int r = 0; r < 16; ++r) {
        float a2 = fmaf(rx[r], rx[r], fmaf(ry[r], ry[r], rz[r] * rz[r]));
        float d2 = fmaxf(a2 + acc[r], 0.0f);
        sum += (wp[r] != 0) ? d2 : 0.0f;
    }
    if (lane == 0) atomicAdd(&loss[b], 0.5f * sum);
}

extern "C" void kernel_launch(void* const* d_in, const int* in_sizes, int n_in,
                              void* d_out, int out_size, void* d_ws, size_t ws_size,
                              hipStream_t stream) {
    const int*   o_w   = (const int*)  d_in[0];
    const float* o_pts = (const float*)d_in[1];
    const int*   t_w   = (const int*)  d_in[2];
    const float* t_pts = (const float*)d_in[3];
    float* loss = (float*)d_out;

    const size_t part_bytes = (size_t)B_ * 2 * GX_ * sizeof(float);   // 4 KB

    if (ws_size >= part_bytes) {
        float* partials = (float*)d_ws;
        dim3 grid(GX_, B_, 2);                                        // (16, 32, 2)
        chamfer_main<<<grid, 512, 0, stream>>>(
            o_w, o_pts, t_w, t_pts, partials);
        chamfer_finish<<<1, 256, 0, stream>>>(partials, loss);
    } else {
        chamfer_zero<<<1, 64, 0, stream>>>(loss);
        dim3 grid(N_ / 64, B_, 2);
        chamfer_nolds<<<grid, 256, 0, stream>>>(
            o_w, o_pts, t_w, t_pts, loss);
    }
}